// Round 1
// baseline (2516.516 us; speedup 1.0000x reference)
//
#include <hip/hip_runtime.h>

#define N_NODES 50000
#define N_EDGES 400000
#define EP (N_EDGES + N_NODES)   // 450000 edges incl. self-loops
#define D 64
#define H 8
#define HD 512
#define NEG_SLOPE 0.2f
#define LN_EPS 1e-5f
#define CHUNK 196
#define SCAN_BLOCKS 256
#define PAD_N 50048

// decode edge id -> (src, dst); ids >= N_EDGES are self-loops
__device__ __forceinline__ void edge_sd(const int* __restrict__ ei, int eid, int& s, int& d) {
    if (eid < N_EDGES) { s = ei[eid]; d = ei[N_EDGES + eid]; }
    else               { s = d = eid - N_EDGES; }
}

// ---------------- CSR build (once per launch) ----------------

__global__ __launch_bounds__(256) void csr_hist(const int* __restrict__ ei, int* __restrict__ counts) {
    int t = blockIdx.x * 256 + threadIdx.x;
    if (t >= EP) return;
    int s, d; edge_sd(ei, t, s, d);
    atomicAdd(&counts[d], 1);
}

__global__ __launch_bounds__(256) void csr_scan1(const int* __restrict__ counts, int* __restrict__ bsum) {
    __shared__ int sd[256];
    int t = threadIdx.x, b = blockIdx.x;
    int idx = b * CHUNK + t;
    sd[t] = (t < CHUNK && idx < N_NODES) ? counts[idx] : 0;
    __syncthreads();
    for (int d = 128; d > 0; d >>= 1) {
        if (t < d) sd[t] += sd[t + d];
        __syncthreads();
    }
    if (t == 0) bsum[b] = sd[0];
}

__global__ __launch_bounds__(256) void csr_scan2(int* __restrict__ bsum) {
    __shared__ int sd[256];
    int t = threadIdx.x;
    sd[t] = bsum[t];
    __syncthreads();
    for (int d = 1; d < 256; d <<= 1) {
        int v = (t >= d) ? sd[t - d] : 0;
        __syncthreads();
        if (t >= d) sd[t] += v;
        __syncthreads();
    }
    bsum[t] = (t > 0) ? sd[t - 1] : 0;   // exclusive block base
}

__global__ __launch_bounds__(256) void csr_scan3(const int* __restrict__ counts, const int* __restrict__ bsum,
                                                 int* __restrict__ offsets, int* __restrict__ cursor) {
    __shared__ int sd[256];
    int t = threadIdx.x, b = blockIdx.x;
    int idx = b * CHUNK + t;
    int v = (t < CHUNK && idx < N_NODES) ? counts[idx] : 0;
    sd[t] = v;
    __syncthreads();
    for (int d = 1; d < 256; d <<= 1) {
        int u = (t >= d) ? sd[t - d] : 0;
        __syncthreads();
        if (t >= d) sd[t] += u;
        __syncthreads();
    }
    if (t < CHUNK && idx < N_NODES) {
        int ex = bsum[b] + sd[t] - v;    // exclusive scan
        offsets[idx] = ex;
        cursor[idx]  = ex;
    }
    if (b == 0 && t == 0) offsets[N_NODES] = EP;
}

__global__ __launch_bounds__(256) void csr_scatter(const int* __restrict__ ei, int* __restrict__ cursor,
                                                   int2* __restrict__ csr) {
    int t = blockIdx.x * 256 + threadIdx.x;
    if (t >= EP) return;
    int s, d; edge_sd(ei, t, s, d);
    int pos = atomicAdd(&cursor[d], 1);
    csr[pos] = make_int2(s, t);          // (src node, edge id)
}

// ---------------- per-layer kernels ----------------

// xl = x @ Wl, xr = x @ Wr ; x:[N,64], W:[64,512] -> [N,512]
// 8 nodes per block, thread t owns output cols {t, t+256} of both xl and xr.
__global__ __launch_bounds__(256) void gemm_xlxr(const float* __restrict__ x,
                                                 const float* __restrict__ Wl, const float* __restrict__ Wr,
                                                 float* __restrict__ xl, float* __restrict__ xr) {
    __shared__ float xs[512];            // 8 nodes x 64 ch
    int t = threadIdx.x;
    int n0 = blockIdx.x * 8;
    for (int q = t; q < 512; q += 256) xs[q] = x[n0 * 64 + q];
    __syncthreads();
    float aL0[8] = {}, aL1[8] = {}, aR0[8] = {}, aR1[8] = {};
    for (int k = 0; k < 64; ++k) {
        float wl0 = Wl[k * 512 + t];
        float wl1 = Wl[k * 512 + t + 256];
        float wr0 = Wr[k * 512 + t];
        float wr1 = Wr[k * 512 + t + 256];
#pragma unroll
        for (int j = 0; j < 8; ++j) {
            float xv = xs[j * 64 + k];
            aL0[j] = fmaf(xv, wl0, aL0[j]);
            aL1[j] = fmaf(xv, wl1, aL1[j]);
            aR0[j] = fmaf(xv, wr0, aR0[j]);
            aR1[j] = fmaf(xv, wr1, aR1[j]);
        }
    }
#pragma unroll
    for (int j = 0; j < 8; ++j) {
        size_t base = (size_t)(n0 + j) * 512;
        xl[base + t]       = aL0[j];
        xl[base + t + 256] = aL1[j];
        xr[base + t]       = aR0[j];
        xr[base + t + 256] = aR1[j];
    }
}

// e[eid,h] = sum_c leaky(xl[src,h,c] + xr[dst,h,c]) * att[h,c]
__global__ __launch_bounds__(256) void edge_logits(const int* __restrict__ ei,
                                                   const float* __restrict__ xl, const float* __restrict__ xr,
                                                   const float* __restrict__ att, float* __restrict__ eL) {
    int t = blockIdx.x * 256 + threadIdx.x;
    if (t >= EP * H) return;
    int eid = t >> 3, h = t & 7;
    int s, d; edge_sd(ei, eid, s, d);
    const float4* pl = (const float4*)(xl + (size_t)s * HD + h * 64);
    const float4* pr = (const float4*)(xr + (size_t)d * HD + h * 64);
    const float4* pa = (const float4*)(att + h * 64);
    float acc = 0.f;
#pragma unroll
    for (int c = 0; c < 16; ++c) {
        float4 l = pl[c], r = pr[c], a = pa[c];
        float v;
        v = l.x + r.x; v = (v > 0.f) ? v : v * NEG_SLOPE; acc = fmaf(v, a.x, acc);
        v = l.y + r.y; v = (v > 0.f) ? v : v * NEG_SLOPE; acc = fmaf(v, a.y, acc);
        v = l.z + r.z; v = (v > 0.f) ? v : v * NEG_SLOPE; acc = fmaf(v, a.z, acc);
        v = l.w + r.w; v = (v > 0.f) ? v : v * NEG_SLOPE; acc = fmaf(v, a.w, acc);
    }
    eL[t] = acc;
}

// One wave per node: softmax over incoming edges (CSR), weighted agg of xl[src],
// head mean + bias + residual + LayerNorm + ReLU, write x_out.
// lane = h*8 + i ; lane owns head h, channels i*8..i*8+7
__global__ __launch_bounds__(256) void node_fused(const float* __restrict__ x_in,
                                                  const float* __restrict__ xl, const float* __restrict__ eL,
                                                  const int* __restrict__ offsets, const int2* __restrict__ csr,
                                                  const float* __restrict__ bias, const float* __restrict__ gamma,
                                                  const float* __restrict__ beta, float* __restrict__ x_out) {
    int n = blockIdx.x * 4 + (threadIdx.x >> 6);
    int lane = threadIdx.x & 63;
    int h = lane >> 3, i = lane & 7;
    int beg = offsets[n], end = offsets[n + 1];

    // pass 1: per-head max over incoming edges
    float m = -3.0e38f;
    for (int j = beg + i; j < end; j += 8)
        m = fmaxf(m, eL[csr[j].y * 8 + h]);
#pragma unroll
    for (int dm = 1; dm < 8; dm <<= 1) m = fmaxf(m, __shfl_xor(m, dm));

    // pass 2: denom
    float ssum = 0.f;
    for (int j = beg + i; j < end; j += 8)
        ssum += __expf(eL[csr[j].y * 8 + h] - m);
#pragma unroll
    for (int dm = 1; dm < 8; dm <<= 1) ssum += __shfl_xor(ssum, dm);
    float inv = 1.0f / ssum;

    // pass 3: weighted aggregation (wave gathers full 512-float xl row per edge, coalesced)
    float acc[8] = {};
    for (int j = beg; j < end; ++j) {
        int2 se = csr[j];
        float alpha = __expf(eL[se.y * 8 + h] - m) * inv;
        const float4* p = (const float4*)(xl + (size_t)se.x * HD + h * 64 + i * 8);
        float4 v0 = p[0], v1 = p[1];
        acc[0] = fmaf(alpha, v0.x, acc[0]);
        acc[1] = fmaf(alpha, v0.y, acc[1]);
        acc[2] = fmaf(alpha, v0.z, acc[2]);
        acc[3] = fmaf(alpha, v0.w, acc[3]);
        acc[4] = fmaf(alpha, v1.x, acc[4]);
        acc[5] = fmaf(alpha, v1.y, acc[5]);
        acc[6] = fmaf(alpha, v1.z, acc[6]);
        acc[7] = fmaf(alpha, v1.w, acc[7]);
    }

    // reduce over heads (xor 8,16,32): every lane with same i gets sum over h
#pragma unroll
    for (int dm = 8; dm < 64; dm <<= 1) {
#pragma unroll
        for (int k2 = 0; k2 < 8; ++k2) acc[k2] += __shfl_xor(acc[k2], dm);
    }

    // head mean + bias + residual; LN stats across channels (xor 1,2,4 covers all 64 ch)
    int cbase = i * 8;
    float v[8];
    float sum = 0.f, sq = 0.f;
#pragma unroll
    for (int k2 = 0; k2 < 8; ++k2) {
        int c = cbase + k2;
        float val = acc[k2] * 0.125f + bias[c] + x_in[n * 64 + c];
        v[k2] = val; sum += val; sq += val * val;
    }
#pragma unroll
    for (int dm = 1; dm < 8; dm <<= 1) { sum += __shfl_xor(sum, dm); sq += __shfl_xor(sq, dm); }
    float mu   = sum * (1.0f / 64.0f);
    float var  = sq * (1.0f / 64.0f) - mu * mu;
    float rstd = rsqrtf(var + LN_EPS);

    if (h == 0) {   // lanes 0..7 hold all 64 channels after head-reduction
        float o[8];
#pragma unroll
        for (int k2 = 0; k2 < 8; ++k2) {
            int c = cbase + k2;
            float y = (v[k2] - mu) * rstd * gamma[c] + beta[c];
            o[k2] = fmaxf(y, 0.f);
        }
        float4* po = (float4*)(x_out + n * 64 + cbase);
        po[0] = make_float4(o[0], o[1], o[2], o[3]);
        po[1] = make_float4(o[4], o[5], o[6], o[7]);
    }
}

// ---------------- host ----------------

extern "C" void kernel_launch(void* const* d_in, const int* in_sizes, int n_in,
                              void* d_out, int out_size, void* d_ws, size_t ws_size,
                              hipStream_t stream) {
    const float* x     = (const float*)d_in[0];
    const float* Wl    = (const float*)d_in[1];
    const float* Wr    = (const float*)d_in[2];
    const float* att   = (const float*)d_in[3];
    const float* b     = (const float*)d_in[4];
    const float* gamma = (const float*)d_in[5];
    const float* beta  = (const float*)d_in[6];
    const int*   ei    = (const int*)d_in[7];
    float* out = (float*)d_out;

    float* ws = (float*)d_ws;
    float* xl = ws;                                  // N*512 floats
    float* xr = xl + (size_t)N_NODES * HD;           // N*512 floats
    float* eL = xr + (size_t)N_NODES * HD;           // EP*H floats
    int* counts  = (int*)(eL + (size_t)EP * H);      // PAD_N ints
    int* offsets = counts + PAD_N;                   // PAD_N ints (N+1 used)
    int* cursor  = offsets + PAD_N;                  // PAD_N ints
    int* bsum    = cursor + PAD_N;                   // 256 ints
    int2* csr    = (int2*)(bsum + 256);              // EP int2 (src, eid)

    // CSR build (dst buckets) — edge list is identical across layers
    hipMemsetAsync(counts, 0, N_NODES * sizeof(int), stream);
    int eb = (EP + 255) / 256;
    csr_hist   <<<eb, 256, 0, stream>>>(ei, counts);
    csr_scan1  <<<SCAN_BLOCKS, 256, 0, stream>>>(counts, bsum);
    csr_scan2  <<<1, 256, 0, stream>>>(bsum);
    csr_scan3  <<<SCAN_BLOCKS, 256, 0, stream>>>(counts, bsum, offsets, cursor);
    csr_scatter<<<eb, 256, 0, stream>>>(ei, cursor, csr);

    const float* xin = x;
    for (int l = 0; l < 3; ++l) {
        gemm_xlxr  <<<N_NODES / 8, 256, 0, stream>>>(xin, Wl + (size_t)l * 64 * HD, Wr + (size_t)l * 64 * HD, xl, xr);
        edge_logits<<<(EP * H + 255) / 256, 256, 0, stream>>>(ei, xl, xr, att + l * (H * D), eL);
        node_fused <<<N_NODES / 4, 256, 0, stream>>>(xin, xl, eL, offsets, csr,
                                                     b + l * D, gamma + l * D, beta + l * D, out);
        xin = out;
    }
}

// Round 2
// 859.974 us; speedup vs baseline: 2.9263x; 2.9263x over previous
//
#include <hip/hip_runtime.h>

#define N_NODES 50000
#define N_EDGES 400000
#define EP (N_EDGES + N_NODES)   // 450000 edges incl. self-loops
#define D 64
#define H 8
#define HD 512
#define NEG_SLOPE 0.2f
#define LN_EPS 1e-5f
#define CHUNK 196
#define SCAN_BLOCKS 256
#define PAD_N 50048

// decode edge id -> (src, dst); ids >= N_EDGES are self-loops
__device__ __forceinline__ void edge_sd(const int* __restrict__ ei, int eid, int& s, int& d) {
    if (eid < N_EDGES) { s = ei[eid]; d = ei[N_EDGES + eid]; }
    else               { s = d = eid - N_EDGES; }
}

// ---------------- CSR build (once per launch) ----------------

__global__ __launch_bounds__(256) void csr_hist(const int* __restrict__ ei, int* __restrict__ counts) {
    int t = blockIdx.x * 256 + threadIdx.x;
    if (t >= EP) return;
    int s, d; edge_sd(ei, t, s, d);
    atomicAdd(&counts[d], 1);
}

__global__ __launch_bounds__(256) void csr_scan1(const int* __restrict__ counts, int* __restrict__ bsum) {
    __shared__ int sd[256];
    int t = threadIdx.x, b = blockIdx.x;
    int idx = b * CHUNK + t;
    sd[t] = (t < CHUNK && idx < N_NODES) ? counts[idx] : 0;
    __syncthreads();
    for (int d = 128; d > 0; d >>= 1) {
        if (t < d) sd[t] += sd[t + d];
        __syncthreads();
    }
    if (t == 0) bsum[b] = sd[0];
}

__global__ __launch_bounds__(256) void csr_scan2(int* __restrict__ bsum) {
    __shared__ int sd[256];
    int t = threadIdx.x;
    sd[t] = bsum[t];
    __syncthreads();
    for (int d = 1; d < 256; d <<= 1) {
        int v = (t >= d) ? sd[t - d] : 0;
        __syncthreads();
        if (t >= d) sd[t] += v;
        __syncthreads();
    }
    bsum[t] = (t > 0) ? sd[t - 1] : 0;   // exclusive block base
}

__global__ __launch_bounds__(256) void csr_scan3(const int* __restrict__ counts, const int* __restrict__ bsum,
                                                 int* __restrict__ offsets, int* __restrict__ cursor) {
    __shared__ int sd[256];
    int t = threadIdx.x, b = blockIdx.x;
    int idx = b * CHUNK + t;
    int v = (t < CHUNK && idx < N_NODES) ? counts[idx] : 0;
    sd[t] = v;
    __syncthreads();
    for (int d = 1; d < 256; d <<= 1) {
        int u = (t >= d) ? sd[t - d] : 0;
        __syncthreads();
        if (t >= d) sd[t] += u;
        __syncthreads();
    }
    if (t < CHUNK && idx < N_NODES) {
        int ex = bsum[b] + sd[t] - v;    // exclusive scan
        offsets[idx] = ex;
        cursor[idx]  = ex;
    }
    if (b == 0 && t == 0) offsets[N_NODES] = EP;
}

__global__ __launch_bounds__(256) void csr_scatter(const int* __restrict__ ei, int* __restrict__ cursor,
                                                   int* __restrict__ csr_src) {
    int t = blockIdx.x * 256 + threadIdx.x;
    if (t >= EP) return;
    int s, d; edge_sd(ei, t, s, d);
    int pos = atomicAdd(&cursor[d], 1);
    csr_src[pos] = s;                    // only src needed (logits computed in-place)
}

// ---------------- per-layer kernels ----------------

// xl = x @ Wl, xr = x @ Wr ; x:[N,64], W:[64,512] -> [N,512]
// 8 nodes per block, thread t owns output cols {t, t+256} of both xl and xr.
__global__ __launch_bounds__(256) void gemm_xlxr(const float* __restrict__ x,
                                                 const float* __restrict__ Wl, const float* __restrict__ Wr,
                                                 float* __restrict__ xl, float* __restrict__ xr) {
    __shared__ float xs[512];            // 8 nodes x 64 ch
    int t = threadIdx.x;
    int n0 = blockIdx.x * 8;
    for (int q = t; q < 512; q += 256) xs[q] = x[n0 * 64 + q];
    __syncthreads();
    float aL0[8] = {}, aL1[8] = {}, aR0[8] = {}, aR1[8] = {};
    for (int k = 0; k < 64; ++k) {
        float wl0 = Wl[k * 512 + t];
        float wl1 = Wl[k * 512 + t + 256];
        float wr0 = Wr[k * 512 + t];
        float wr1 = Wr[k * 512 + t + 256];
#pragma unroll
        for (int j = 0; j < 8; ++j) {
            float xv = xs[j * 64 + k];
            aL0[j] = fmaf(xv, wl0, aL0[j]);
            aL1[j] = fmaf(xv, wl1, aL1[j]);
            aR0[j] = fmaf(xv, wr0, aR0[j]);
            aR1[j] = fmaf(xv, wr1, aR1[j]);
        }
    }
#pragma unroll
    for (int j = 0; j < 8; ++j) {
        size_t base = (size_t)(n0 + j) * 512;
        xl[base + t]       = aL0[j];
        xl[base + t + 256] = aL1[j];
        xr[base + t]       = aR0[j];
        xr[base + t + 256] = aR1[j];
    }
}

// One wave per node. Single pass over incoming edges with ONLINE softmax:
// per edge, the wave gathers xl[src] (2 KB, coalesced), computes the per-head
// logit in-register (xr[n] + att are loop-invariant), and updates running
// (max, denom, rescaled weighted accumulator). Then head-mean + bias +
// residual + LayerNorm + ReLU.
// lane = h*8 + i ; lane owns head h, channels i*8..i*8+7
__global__ __launch_bounds__(256) void node_fused(const float* __restrict__ x_in,
                                                  const float* __restrict__ xl, const float* __restrict__ xr,
                                                  const float* __restrict__ att,
                                                  const int* __restrict__ offsets, const int* __restrict__ csr_src,
                                                  const float* __restrict__ bias, const float* __restrict__ gamma,
                                                  const float* __restrict__ beta, float* __restrict__ x_out) {
    int n = blockIdx.x * 4 + (threadIdx.x >> 6);
    int lane = threadIdx.x & 63;
    int h = lane >> 3, i = lane & 3 | (lane & 7);   // i = lane & 7
    i = lane & 7;
    int beg = offsets[n], end = offsets[n + 1];

    // loop-invariant: xr row of this node, attention vector (8 channels each)
    const float4* pr = (const float4*)(xr + (size_t)n * HD + h * 64 + i * 8);
    float4 r0 = pr[0], r1 = pr[1];
    const float4* pa = (const float4*)(att + h * 64 + i * 8);
    float4 a0 = pa[0], a1 = pa[1];

    float m = -3.0e38f, den = 0.f;
    float acc[8] = {};

    for (int j = beg; j < end; ++j) {
        int s = csr_src[j];                               // wave-uniform (scalar load)
        const float4* p = (const float4*)(xl + (size_t)s * HD + h * 64 + i * 8);
        float4 v0 = p[0], v1 = p[1];

        // partial logit over this lane's 8 channels
        float t, pdot = 0.f;
        t = v0.x + r0.x; t = (t > 0.f) ? t : t * NEG_SLOPE; pdot = fmaf(t, a0.x, pdot);
        t = v0.y + r0.y; t = (t > 0.f) ? t : t * NEG_SLOPE; pdot = fmaf(t, a0.y, pdot);
        t = v0.z + r0.z; t = (t > 0.f) ? t : t * NEG_SLOPE; pdot = fmaf(t, a0.z, pdot);
        t = v0.w + r0.w; t = (t > 0.f) ? t : t * NEG_SLOPE; pdot = fmaf(t, a0.w, pdot);
        t = v1.x + r1.x; t = (t > 0.f) ? t : t * NEG_SLOPE; pdot = fmaf(t, a1.x, pdot);
        t = v1.y + r1.y; t = (t > 0.f) ? t : t * NEG_SLOPE; pdot = fmaf(t, a1.y, pdot);
        t = v1.z + r1.z; t = (t > 0.f) ? t : t * NEG_SLOPE; pdot = fmaf(t, a1.z, pdot);
        t = v1.w + r1.w; t = (t > 0.f) ? t : t * NEG_SLOPE; pdot = fmaf(t, a1.w, pdot);
        // reduce over the 8 channel-group lanes of this head
#pragma unroll
        for (int dm = 1; dm < 8; dm <<= 1) pdot += __shfl_xor(pdot, dm);
        float e = pdot;

        // online softmax update (all 8 lanes of the head group stay coherent)
        float mn = fmaxf(m, e);
        float scale = __expf(m - mn);     // first iter: exp(-3e38-e) -> 0
        float w = __expf(e - mn);
        den = den * scale + w;
        acc[0] = fmaf(acc[0], scale, w * v0.x);
        acc[1] = fmaf(acc[1], scale, w * v0.y);
        acc[2] = fmaf(acc[2], scale, w * v0.z);
        acc[3] = fmaf(acc[3], scale, w * v0.w);
        acc[4] = fmaf(acc[4], scale, w * v1.x);
        acc[5] = fmaf(acc[5], scale, w * v1.y);
        acc[6] = fmaf(acc[6], scale, w * v1.z);
        acc[7] = fmaf(acc[7], scale, w * v1.w);
        m = mn;
    }

    // normalize per head, then reduce over heads (xor 8,16,32)
    float invden = 1.0f / den;
#pragma unroll
    for (int k2 = 0; k2 < 8; ++k2) acc[k2] *= invden;
#pragma unroll
    for (int dm = 8; dm < 64; dm <<= 1) {
#pragma unroll
        for (int k2 = 0; k2 < 8; ++k2) acc[k2] += __shfl_xor(acc[k2], dm);
    }

    // head mean + bias + residual; LN stats across channels (xor 1,2,4 covers all 64 ch)
    int cbase = i * 8;
    float v[8];
    float sum = 0.f, sq = 0.f;
#pragma unroll
    for (int k2 = 0; k2 < 8; ++k2) {
        int c = cbase + k2;
        float val = acc[k2] * 0.125f + bias[c] + x_in[n * 64 + c];
        v[k2] = val; sum += val; sq += val * val;
    }
#pragma unroll
    for (int dm = 1; dm < 8; dm <<= 1) { sum += __shfl_xor(sum, dm); sq += __shfl_xor(sq, dm); }
    float mu   = sum * (1.0f / 64.0f);
    float var  = sq * (1.0f / 64.0f) - mu * mu;
    float rstd = rsqrtf(var + LN_EPS);

    if (h == 0) {   // lanes 0..7 hold all 64 channels after head-reduction
        float o[8];
#pragma unroll
        for (int k2 = 0; k2 < 8; ++k2) {
            int c = cbase + k2;
            float y = (v[k2] - mu) * rstd * gamma[c] + beta[c];
            o[k2] = fmaxf(y, 0.f);
        }
        float4* po = (float4*)(x_out + n * 64 + cbase);
        po[0] = make_float4(o[0], o[1], o[2], o[3]);
        po[1] = make_float4(o[4], o[5], o[6], o[7]);
    }
}

// ---------------- host ----------------

extern "C" void kernel_launch(void* const* d_in, const int* in_sizes, int n_in,
                              void* d_out, int out_size, void* d_ws, size_t ws_size,
                              hipStream_t stream) {
    const float* x     = (const float*)d_in[0];
    const float* Wl    = (const float*)d_in[1];
    const float* Wr    = (const float*)d_in[2];
    const float* att   = (const float*)d_in[3];
    const float* b     = (const float*)d_in[4];
    const float* gamma = (const float*)d_in[5];
    const float* beta  = (const float*)d_in[6];
    const int*   ei    = (const int*)d_in[7];
    float* out = (float*)d_out;

    float* ws = (float*)d_ws;
    float* xl = ws;                                  // N*512 floats
    float* xr = xl + (size_t)N_NODES * HD;           // N*512 floats
    int* counts  = (int*)(xr + (size_t)N_NODES * HD);// PAD_N ints
    int* offsets = counts + PAD_N;                   // PAD_N ints (N+1 used)
    int* cursor  = offsets + PAD_N;                  // PAD_N ints
    int* bsum    = cursor + PAD_N;                   // 256 ints
    int* csr_src = bsum + 256;                       // EP ints (src per CSR slot)

    // CSR build (dst buckets) — edge list is identical across layers
    hipMemsetAsync(counts, 0, N_NODES * sizeof(int), stream);
    int eb = (EP + 255) / 256;
    csr_hist   <<<eb, 256, 0, stream>>>(ei, counts);
    csr_scan1  <<<SCAN_BLOCKS, 256, 0, stream>>>(counts, bsum);
    csr_scan2  <<<1, 256, 0, stream>>>(bsum);
    csr_scan3  <<<SCAN_BLOCKS, 256, 0, stream>>>(counts, bsum, offsets, cursor);
    csr_scatter<<<eb, 256, 0, stream>>>(ei, cursor, csr_src);

    const float* xin = x;
    for (int l = 0; l < 3; ++l) {
        gemm_xlxr <<<N_NODES / 8, 256, 0, stream>>>(xin, Wl + (size_t)l * 64 * HD, Wr + (size_t)l * 64 * HD, xl, xr);
        node_fused<<<N_NODES / 4, 256, 0, stream>>>(xin, xl, xr, att + l * (H * D), offsets, csr_src,
                                                    b + l * D, gamma + l * D, beta + l * D, out);
        xin = out;
    }
}

// Round 3
// 592.644 us; speedup vs baseline: 4.2463x; 1.4511x over previous
//
#include <hip/hip_runtime.h>

#define N_NODES 50000
#define N_EDGES 400000
#define EP (N_EDGES + N_NODES)   // 450000 edges incl. self-loops
#define D 64
#define H 8
#define NEG_SLOPE 0.2f
#define LN_EPS 1e-5f
#define CHUNK 196
#define SCAN_BLOCKS 256
#define PAD_N 50048

typedef unsigned short ushort_t;
typedef unsigned int uint_t;
typedef __attribute__((ext_vector_type(8))) short short8;
typedef __attribute__((ext_vector_type(4))) float f32x4;

__device__ __forceinline__ ushort_t f2bf(float f) {
    uint_t u = __float_as_uint(f);
    u += 0x7fffu + ((u >> 16) & 1u);          // round-to-nearest-even
    return (ushort_t)(u >> 16);
}
__device__ __forceinline__ float bflo(uint_t u) { return __uint_as_float(u << 16); }
__device__ __forceinline__ float bfhi(uint_t u) { return __uint_as_float(u & 0xffff0000u); }

// decode edge id -> (src, dst); ids >= N_EDGES are self-loops
__device__ __forceinline__ void edge_sd(const int* __restrict__ ei, int eid, int& s, int& d) {
    if (eid < N_EDGES) { s = ei[eid]; d = ei[N_EDGES + eid]; }
    else               { s = d = eid - N_EDGES; }
}

// ---------------- CSR build (once per launch) ----------------

__global__ __launch_bounds__(256) void csr_hist(const int* __restrict__ ei, int* __restrict__ counts) {
    int t = blockIdx.x * 256 + threadIdx.x;
    if (t >= EP) return;
    int s, d; edge_sd(ei, t, s, d);
    atomicAdd(&counts[d], 1);
}

__global__ __launch_bounds__(256) void csr_scan1(const int* __restrict__ counts, int* __restrict__ bsum) {
    __shared__ int sd[256];
    int t = threadIdx.x, b = blockIdx.x;
    int idx = b * CHUNK + t;
    sd[t] = (t < CHUNK && idx < N_NODES) ? counts[idx] : 0;
    __syncthreads();
    for (int d = 128; d > 0; d >>= 1) {
        if (t < d) sd[t] += sd[t + d];
        __syncthreads();
    }
    if (t == 0) bsum[b] = sd[0];
}

__global__ __launch_bounds__(256) void csr_scan2(int* __restrict__ bsum) {
    __shared__ int sd[256];
    int t = threadIdx.x;
    sd[t] = bsum[t];
    __syncthreads();
    for (int d = 1; d < 256; d <<= 1) {
        int v = (t >= d) ? sd[t - d] : 0;
        __syncthreads();
        if (t >= d) sd[t] += v;
        __syncthreads();
    }
    bsum[t] = (t > 0) ? sd[t - 1] : 0;   // exclusive block base
}

__global__ __launch_bounds__(256) void csr_scan3(const int* __restrict__ counts, const int* __restrict__ bsum,
                                                 int* __restrict__ offsets, int* __restrict__ cursor) {
    __shared__ int sd[256];
    int t = threadIdx.x, b = blockIdx.x;
    int idx = b * CHUNK + t;
    int v = (t < CHUNK && idx < N_NODES) ? counts[idx] : 0;
    sd[t] = v;
    __syncthreads();
    for (int d = 1; d < 256; d <<= 1) {
        int u = (t >= d) ? sd[t - d] : 0;
        __syncthreads();
        if (t >= d) sd[t] += u;
        __syncthreads();
    }
    if (t < CHUNK && idx < N_NODES) {
        int ex = bsum[b] + sd[t] - v;    // exclusive scan
        offsets[idx] = ex;
        cursor[idx]  = ex;
    }
    if (b == 0 && t == 0) offsets[N_NODES] = EP;
}

__global__ __launch_bounds__(256) void csr_scatter(const int* __restrict__ ei, int* __restrict__ cursor,
                                                   int* __restrict__ csr_src) {
    int t = blockIdx.x * 256 + threadIdx.x;
    if (t >= EP) return;
    int s, d; edge_sd(ei, t, s, d);
    int pos = atomicAdd(&cursor[d], 1);
    csr_src[pos] = s;
}

// ---------------- prep: bf16 conversions ----------------

// Wt[l][col(1024)][k(64)] bf16  <-  Wl[l][k][col<512] / Wr[l][k][col-512] fp32
__global__ __launch_bounds__(256) void prep_w(const float* __restrict__ Wl, const float* __restrict__ Wr,
                                              ushort_t* __restrict__ Wt) {
    int t = blockIdx.x * 256 + threadIdx.x;
    if (t >= 3 * 1024 * 64) return;
    int l = t >> 16, rem = t & 65535, col = rem >> 6, k = rem & 63;
    float v = (col < 512) ? Wl[((size_t)l * 64 + k) * 512 + col]
                          : Wr[((size_t)l * 64 + k) * 512 + (col - 512)];
    Wt[t] = f2bf(v);
}

__global__ __launch_bounds__(256) void conv_x(const float* __restrict__ x, ushort_t* __restrict__ xb) {
    int t = blockIdx.x * 256 + threadIdx.x;
    if (t < N_NODES * 64) xb[t] = f2bf(x[t]);
}

// ---------------- MFMA GEMM: xlr[n][0:512]=x@Wl, [512:1024]=x@Wr (bf16) ----------------
// block = 4 waves, 16-node tile; wave w covers cols [w*256, w*256+256).
// A frag: A[m=lane&15][k=quad*8+j]; B frag: B[k=quad*8+j][n=lane&15] from Wt[n][k];
// D: col=lane&15, row=quad*4+reg.
__global__ __launch_bounds__(256) void gemm_mfma(const ushort_t* __restrict__ xb,
                                                 const ushort_t* __restrict__ Wt,
                                                 ushort_t* __restrict__ xlr) {
    int lane = threadIdx.x & 63;
    int w = threadIdx.x >> 6;
    int m = lane & 15, q = lane >> 4;
    int n0 = blockIdx.x * 16;

    const short8 a0 = *(const short8*)(xb + (size_t)(n0 + m) * 64 + q * 8);
    const short8 a1 = *(const short8*)(xb + (size_t)(n0 + m) * 64 + 32 + q * 8);

    for (int ct = 0; ct < 16; ++ct) {
        int col = w * 256 + ct * 16 + m;
        const short8 b0 = *(const short8*)(Wt + (size_t)col * 64 + q * 8);
        const short8 b1 = *(const short8*)(Wt + (size_t)col * 64 + 32 + q * 8);
        f32x4 acc = {0.f, 0.f, 0.f, 0.f};
        acc = __builtin_amdgcn_mfma_f32_16x16x32_bf16(a0, b0, acc, 0, 0, 0);
        acc = __builtin_amdgcn_mfma_f32_16x16x32_bf16(a1, b1, acc, 0, 0, 0);
#pragma unroll
        for (int r = 0; r < 4; ++r)
            xlr[(size_t)(n0 + q * 4 + r) * 1024 + col] = f2bf(acc[r]);
    }
}

// ---------------- fused node kernel (online softmax, bf16 gathers) ----------------
// One wave per node. lane = h*8 + i; lane owns head h, channels i*8..i*8+7.
__global__ __launch_bounds__(256) void node_fused(const float* __restrict__ x_in,
                                                  const ushort_t* __restrict__ xlr,
                                                  const float* __restrict__ att,
                                                  const int* __restrict__ offsets, const int* __restrict__ csr_src,
                                                  const float* __restrict__ bias, const float* __restrict__ gamma,
                                                  const float* __restrict__ beta, float* __restrict__ x_out,
                                                  ushort_t* __restrict__ xb_out) {
    int n = blockIdx.x * 4 + (threadIdx.x >> 6);
    int lane = threadIdx.x & 63;
    int h = lane >> 3, i = lane & 7;
    int beg = offsets[n], end = offsets[n + 1];

    // loop-invariant: xr row of this node (bf16), attention vector (fp32)
    uint4 ru = *(const uint4*)(xlr + (size_t)n * 1024 + 512 + h * 64 + i * 8);
    float r0 = bflo(ru.x), r1 = bfhi(ru.x), r2 = bflo(ru.y), r3 = bfhi(ru.y),
          r4 = bflo(ru.z), r5 = bfhi(ru.z), r6 = bflo(ru.w), r7 = bfhi(ru.w);
    const float4* pa = (const float4*)(att + h * 64 + i * 8);
    float4 a0 = pa[0], a1 = pa[1];

    float mx = -3.0e38f, den = 0.f;
    float acc[8] = {};

    for (int j = beg; j < end; ++j) {
        int s = csr_src[j];
        uint4 uv = *(const uint4*)(xlr + (size_t)s * 1024 + h * 64 + i * 8);
        float v0 = bflo(uv.x), v1 = bfhi(uv.x), v2 = bflo(uv.y), v3 = bfhi(uv.y),
              v4 = bflo(uv.z), v5 = bfhi(uv.z), v6 = bflo(uv.w), v7 = bfhi(uv.w);

        // partial logit over this lane's 8 channels
        float t, pdot = 0.f;
        t = v0 + r0; t = (t > 0.f) ? t : t * NEG_SLOPE; pdot = fmaf(t, a0.x, pdot);
        t = v1 + r1; t = (t > 0.f) ? t : t * NEG_SLOPE; pdot = fmaf(t, a0.y, pdot);
        t = v2 + r2; t = (t > 0.f) ? t : t * NEG_SLOPE; pdot = fmaf(t, a0.z, pdot);
        t = v3 + r3; t = (t > 0.f) ? t : t * NEG_SLOPE; pdot = fmaf(t, a0.w, pdot);
        t = v4 + r4; t = (t > 0.f) ? t : t * NEG_SLOPE; pdot = fmaf(t, a1.x, pdot);
        t = v5 + r5; t = (t > 0.f) ? t : t * NEG_SLOPE; pdot = fmaf(t, a1.y, pdot);
        t = v6 + r6; t = (t > 0.f) ? t : t * NEG_SLOPE; pdot = fmaf(t, a1.z, pdot);
        t = v7 + r7; t = (t > 0.f) ? t : t * NEG_SLOPE; pdot = fmaf(t, a1.w, pdot);
#pragma unroll
        for (int dm = 1; dm < 8; dm <<= 1) pdot += __shfl_xor(pdot, dm);
        float e = pdot;

        // online softmax update
        float mn = fmaxf(mx, e);
        float scale = __expf(mx - mn);
        float wgt = __expf(e - mn);
        den = den * scale + wgt;
        acc[0] = fmaf(acc[0], scale, wgt * v0);
        acc[1] = fmaf(acc[1], scale, wgt * v1);
        acc[2] = fmaf(acc[2], scale, wgt * v2);
        acc[3] = fmaf(acc[3], scale, wgt * v3);
        acc[4] = fmaf(acc[4], scale, wgt * v4);
        acc[5] = fmaf(acc[5], scale, wgt * v5);
        acc[6] = fmaf(acc[6], scale, wgt * v6);
        acc[7] = fmaf(acc[7], scale, wgt * v7);
        mx = mn;
    }

    // normalize per head, reduce over heads
    float invden = 1.0f / den;
#pragma unroll
    for (int k2 = 0; k2 < 8; ++k2) acc[k2] *= invden;
#pragma unroll
    for (int dm = 8; dm < 64; dm <<= 1) {
#pragma unroll
        for (int k2 = 0; k2 < 8; ++k2) acc[k2] += __shfl_xor(acc[k2], dm);
    }

    // head mean + bias + residual; LN stats across channels
    int cbase = i * 8;
    float v[8];
    float sum = 0.f, sq = 0.f;
#pragma unroll
    for (int k2 = 0; k2 < 8; ++k2) {
        int c = cbase + k2;
        float val = acc[k2] * 0.125f + bias[c] + x_in[n * 64 + c];
        v[k2] = val; sum += val; sq += val * val;
    }
#pragma unroll
    for (int dm = 1; dm < 8; dm <<= 1) { sum += __shfl_xor(sum, dm); sq += __shfl_xor(sq, dm); }
    float mu   = sum * (1.0f / 64.0f);
    float var  = sq * (1.0f / 64.0f) - mu * mu;
    float rstd = rsqrtf(var + LN_EPS);

    if (h == 0) {   // lanes 0..7 hold all 64 channels after head-reduction
        float o[8];
#pragma unroll
        for (int k2 = 0; k2 < 8; ++k2) {
            int c = cbase + k2;
            float y = (v[k2] - mu) * rstd * gamma[c] + beta[c];
            o[k2] = fmaxf(y, 0.f);
        }
        float4* po = (float4*)(x_out + n * 64 + cbase);
        po[0] = make_float4(o[0], o[1], o[2], o[3]);
        po[1] = make_float4(o[4], o[5], o[6], o[7]);
        // bf16 copy for the next layer's MFMA GEMM
        uint_t w0 = (uint_t)f2bf(o[0]) | ((uint_t)f2bf(o[1]) << 16);
        uint_t w1 = (uint_t)f2bf(o[2]) | ((uint_t)f2bf(o[3]) << 16);
        uint_t w2 = (uint_t)f2bf(o[4]) | ((uint_t)f2bf(o[5]) << 16);
        uint_t w3 = (uint_t)f2bf(o[6]) | ((uint_t)f2bf(o[7]) << 16);
        *(uint4*)(xb_out + (size_t)n * 64 + cbase) = make_uint4(w0, w1, w2, w3);
    }
}

// ---------------- host ----------------

extern "C" void kernel_launch(void* const* d_in, const int* in_sizes, int n_in,
                              void* d_out, int out_size, void* d_ws, size_t ws_size,
                              hipStream_t stream) {
    const float* x     = (const float*)d_in[0];
    const float* Wl    = (const float*)d_in[1];
    const float* Wr    = (const float*)d_in[2];
    const float* att   = (const float*)d_in[3];
    const float* b     = (const float*)d_in[4];
    const float* gamma = (const float*)d_in[5];
    const float* beta  = (const float*)d_in[6];
    const int*   ei    = (const int*)d_in[7];
    float* out = (float*)d_out;

    ushort_t* xlr = (ushort_t*)d_ws;                       // N*1024 bf16
    ushort_t* xb  = xlr + (size_t)N_NODES * 1024;          // N*64 bf16
    ushort_t* Wt  = xb + (size_t)N_NODES * 64;             // 3*1024*64 bf16
    int* counts   = (int*)(Wt + 3 * 1024 * 64);            // PAD_N
    int* offsets  = counts + PAD_N;                        // PAD_N (N+1 used)
    int* cursor   = offsets + PAD_N;                       // PAD_N
    int* bsum     = cursor + PAD_N;                        // 256
    int* csr_src  = bsum + 256;                            // EP

    // CSR build (dst buckets)
    hipMemsetAsync(counts, 0, N_NODES * sizeof(int), stream);
    int eb = (EP + 255) / 256;
    csr_hist   <<<eb, 256, 0, stream>>>(ei, counts);
    csr_scan1  <<<SCAN_BLOCKS, 256, 0, stream>>>(counts, bsum);
    csr_scan2  <<<1, 256, 0, stream>>>(bsum);
    csr_scan3  <<<SCAN_BLOCKS, 256, 0, stream>>>(counts, bsum, offsets, cursor);
    csr_scatter<<<eb, 256, 0, stream>>>(ei, cursor, csr_src);

    // bf16 prep
    prep_w <<<(3 * 1024 * 64 + 255) / 256, 256, 0, stream>>>(Wl, Wr, Wt);
    conv_x <<<(N_NODES * 64 + 255) / 256, 256, 0, stream>>>(x, xb);

    const float* xin = x;
    for (int l = 0; l < 3; ++l) {
        gemm_mfma <<<N_NODES / 16, 256, 0, stream>>>(xb, Wt + (size_t)l * 1024 * 64, xlr);
        node_fused<<<N_NODES / 4, 256, 0, stream>>>(xin, xlr, att + l * (H * D), offsets, csr_src,
                                                    b + l * D, gamma + l * D, beta + l * D, out, xb);
        xin = out;
    }
}